// Round 12
// baseline (1070.237 us; speedup 1.0000x reference)
//
#include <hip/hip_runtime.h>

#define NB 128
#define NL 256
#define NH 512
#define NMAX 256

typedef __attribute__((ext_vector_type(8))) short s8v;
typedef __attribute__((ext_vector_type(4))) float f4v;

struct Params {
  const int* widx;
  const float* bias[5];
  const unsigned short* wbf;
  const unsigned short* embbf;
  const unsigned short* hcprev;
  unsigned short* hcout;
  float* out;
  float* fh;
  float* fc;
};

struct TailP {
  const float* bias[5];
  const unsigned short* wbf;
  unsigned short* hc[9];           // hc[k] = output of level k (hc[2] = input to L3)
  unsigned short* part[9];         // split-K partials per level
  float* out;
  float* fh;
  float* fc;
  int* bar;                        // [cnt, gen]
};

struct PrepParams {
  const float* u[10];
  const float* emb;
  unsigned short* wdst;
  unsigned short* edst;
};

__device__ __forceinline__ float bf2f(unsigned short u) {
  union { unsigned int i; float f; } v;
  v.i = ((unsigned int)u) << 16;
  return v.f;
}
__device__ __forceinline__ unsigned short f2bf(float f) {
  union { float f; unsigned int i; } v;
  v.f = f;
  unsigned int x = v.i;
  x += 0x7fffu + ((x >> 16) & 1u);   // RNE
  return (unsigned short)(x >> 16);
}
__device__ __forceinline__ s8v pack8(f4v a, f4v b) {
  s8v r;
  r[0] = (short)f2bf(a[0]); r[1] = (short)f2bf(a[1]);
  r[2] = (short)f2bf(a[2]); r[3] = (short)f2bf(a[3]);
  r[4] = (short)f2bf(b[0]); r[5] = (short)f2bf(b[1]);
  r[6] = (short)f2bf(b[2]); r[7] = (short)f2bf(b[3]);
  return r;
}
__device__ __forceinline__ float sigf(float x) {
  return 1.f / (1.f + __expf(-x));
}
__device__ __forceinline__ void glds16(const void* g, void* l) {
  __builtin_amdgcn_global_load_lds(
      (const __attribute__((address_space(1))) unsigned int*)g,
      (__attribute__((address_space(3))) unsigned int*)l, 16, 0, 0);
}

// Grid barrier: arrive + generation. All 256 blocks resident (grid=256 at
// 57KB LDS => capacity 512).  threadfence on both sides for cross-XCD L2
// visibility (G16).
__device__ __forceinline__ void gbar(int* bar) {
  __threadfence();
  __syncthreads();
  if (threadIdx.x == 0) {
    int g = __hip_atomic_load(bar + 1, __ATOMIC_RELAXED, __HIP_MEMORY_SCOPE_AGENT);
    if (__hip_atomic_fetch_add(bar, 1, __ATOMIC_ACQ_REL, __HIP_MEMORY_SCOPE_AGENT) == 255) {
      __hip_atomic_store(bar, 0, __ATOMIC_RELAXED, __HIP_MEMORY_SCOPE_AGENT);
      __hip_atomic_fetch_add(bar + 1, 1, __ATOMIC_ACQ_REL, __HIP_MEMORY_SCOPE_AGENT);
    } else {
      while (__hip_atomic_load(bar + 1, __ATOMIC_ACQUIRE, __HIP_MEMORY_SCOPE_AGENT) == g)
        __builtin_amdgcn_s_sleep(8);
    }
  }
  __syncthreads();
  __threadfence();
}

// One prep pass: 10 (H,H) weights + the full emb table, f32 -> bf16.
__global__ __launch_bounds__(256) void prep_cvt(PrepParams pp) {
  int gid = blockIdx.x * 256 + threadIdx.x;
  const float* s;
  unsigned short* d;
  if (gid < 327680) {
    int mat = gid >> 15, off = (gid & 32767) * 8;
    s = pp.u[mat] + off;
    d = pp.wdst + (size_t)mat * NH * NH + off;
  } else {
    size_t off = (size_t)(gid - 327680) * 8;
    s = pp.emb + off;
    d = pp.edst + off;
  }
  f4v x0 = *(const f4v*)s;
  f4v x1 = *(const f4v*)(s + 4);
  *(s8v*)d = pack8(x0, x1);
}

// Post-order position of internal node (k, j): pos = (j+1)*2^k - 2 - popcount(j).
// Output column = pos + 1 (column 0 duplicates node (1,0)).

// ----- Standalone GEMM kernel for levels 1-2 (r11 structure, KS=1) -----
template<int LEVEL, int BM>
__global__ __launch_bounds__(BM * 2, 2)
void lstm_level(Params p) {
  constexpr int NK = NL >> LEVEL;
  constexpr int LOGNK = 8 - LEVEL;
  constexpr int NKP = NL >> (LEVEL - 1);
  constexpr int M = NB * NK;
  constexpr int W = BM / 32;
  constexpr int ASUB = BM * 64;
  constexpr int BUFSZ = ASUB + 20480;
  __shared__ __align__(16) unsigned char lds[2 * BUFSZ];

  const int tid = threadIdx.x;
  const int wid = tid >> 6;
  const int lane = tid & 63;
  const int lhi = lane >> 4, llo = lane & 15;
  const int mh = (BM == 256) ? (wid & 1) : 0;
  const int q  = (BM == 256) ? (wid >> 1) : wid;
  const int bm = blockIdx.x, ht = blockIdx.y;

  const unsigned short* abase = (LEVEL == 1) ? p.embbf : p.hcprev;

  int aOffL[2], aOffR[2];
#pragma unroll
  for (int ii = 0; ii < 2; ++ii) {
    int gi = ii * W + wid;
    int ar = gi * 16 + (lane >> 2);
    int ck = (lane & 3) ^ ((ar >> 1) & 3);
    int am = bm * BM + ar; if (am > M - 1) am = M - 1;
    int b = am >> LOGNK, j = am & (NK - 1);
    if constexpr (LEVEL == 1) {
      aOffL[ii] = p.widx[b * NL + 2 * j] * NH + ck * 8;
      aOffR[ii] = p.widx[b * NL + 2 * j + 1] * NH + ck * 8;
    } else {
      int base = (b * NKP + 2 * j) * (2 * NH);
      aOffL[ii] = base + ck * 8;
      aOffR[ii] = base + 2 * NH + ck * 8;
    }
  }

  constexpr int BI = (20 + W - 1) / W;
  int bOff[BI];
#pragma unroll
  for (int ii = 0; ii < BI; ++ii) {
    int gi = ii * W + wid;
    if (gi < 20) {
      int r = gi * 16 + (lane >> 2);
      int gg = gi >> 2;
      int ck = (lane & 3) ^ ((r >> 1) & 3);
      bOff[ii] = ((2 * gg) * NH + (ht * 64 + (r & 63))) * NH + ck * 8;
    } else bOff[ii] = 0;
  }

  auto do_stage = [&](int buf, int tt) {
    unsigned char* base = lds + buf * BUFSZ;
    const int kw = (tt & 15) * 32;
    const int* ao = (tt < 16) ? aOffL : aOffR;
#pragma unroll
    for (int ii = 0; ii < 2; ++ii)
      glds16(abase + ao[ii] + kw, base + (ii * W + wid) * 1024);
    const size_t wsel = (size_t)(tt >> 4) * NH * NH;
#pragma unroll
    for (int ii = 0; ii < BI; ++ii) {
      int gi = ii * W + wid;
      if (gi < 20)
        glds16(p.wbf + wsel + bOff[ii] + kw, base + ASUB + gi * 1024);
    }
  };

  int aoff[8], boff[5];
#pragma unroll
  for (int fm = 0; fm < 8; ++fm) {
    int r = mh * 128 + fm * 16 + llo;
    aoff[fm] = r * 64 + ((lhi ^ ((r >> 1) & 3)) << 4);
  }
#pragma unroll
  for (int g = 0; g < 5; ++g) {
    int r = g * 64 + q * 16 + llo;
    boff[g] = ASUB + r * 64 + ((lhi ^ ((r >> 1) & 3)) << 4);
  }

  f4v acc[8][5];
#pragma unroll
  for (int fm = 0; fm < 8; ++fm)
#pragma unroll
    for (int g = 0; g < 5; ++g)
      acc[fm][g] = (f4v){0.f, 0.f, 0.f, 0.f};

  auto compute = [&](int buf) {
    const unsigned char* base = lds + buf * BUFSZ;
    s8v af[8], bv[5];
#pragma unroll
    for (int fm = 0; fm < 8; ++fm) af[fm] = *(const s8v*)(base + aoff[fm]);
#pragma unroll
    for (int g = 0; g < 5; ++g)  bv[g] = *(const s8v*)(base + boff[g]);
    __builtin_amdgcn_s_setprio(1);
#pragma unroll
    for (int fm = 0; fm < 8; ++fm)
#pragma unroll
      for (int g = 0; g < 5; ++g)
        acc[fm][g] = __builtin_amdgcn_mfma_f32_16x16x32_bf16(
            af[fm], bv[g], acc[fm][g], 0, 0, 0);
    __builtin_amdgcn_s_setprio(0);
  };

  do_stage(0, 0);
  __syncthreads();
  for (int t = 0; t < 32; ++t) {
    const int cur = t & 1;
    if (t + 1 < 32) do_stage(cur ^ 1, t + 1);
    compute(cur);
    __syncthreads();
  }

  const int hd = ht * 64 + q * 16 + llo;
  float bb[5];
#pragma unroll
  for (int g = 0; g < 5; ++g) bb[g] = p.bias[g][hd];

#pragma unroll
  for (int fm = 0; fm < 8; ++fm) {
#pragma unroll
    for (int jj = 0; jj < 4; ++jj) {
      int m = bm * BM + mh * 128 + fm * 16 + lhi * 4 + jj;
      if (m < M) {
        int b = m >> LOGNK, j = m & (NK - 1);
        float zi  = acc[fm][0][jj] + bb[0];
        float zfl = acc[fm][1][jj] + bb[1];
        float zfr = acc[fm][2][jj] + bb[2];
        float zo  = acc[fm][3][jj] + bb[3];
        float zc  = acc[fm][4][jj] + bb[4];
        float cl = 0.5f, cr = 0.5f;
        if constexpr (LEVEL > 1) {
          const unsigned short* cb =
              p.hcprev + ((size_t)b * NKP + 2 * j) * (2 * NH) + NH;
          cl = bf2f(cb[hd]);
          cr = bf2f(cb[2 * NH + hd]);
        }
        float cnew = sigf(zi) * tanhf(zc) + sigf(zfl) * cl + sigf(zfr) * cr;
        float hnew = sigf(zo) * tanhf(cnew);
        unsigned short* orow = p.hcout + ((size_t)b * NK + j) * (2 * NH);
        orow[hd] = f2bf(hnew);
        orow[NH + hd] = f2bf(cnew);
        int colout = (((j + 1) << LEVEL) - 2 - __popc(j)) + 1;
        p.out[((size_t)b * NMAX + colout) * NH + hd] = hnew;
        if (LEVEL == 1 && j == 0) p.out[(size_t)b * NMAX * NH + hd] = hnew;
      }
    }
  }
}

// ----- Persistent tail: levels 3-8 fused, grid = 256 blocks x 256 thr -----
template<int LEVEL, int KS>
__device__ void tail_gemm(const TailP& tp, unsigned char* lds, int bid) {
  constexpr int NK = NL >> LEVEL;
  constexpr int LOGNK = 8 - LEVEL;
  constexpr int NKP = NL >> (LEVEL - 1);
  constexpr int M = NB * NK;
  constexpr int BMX = M / 128;
  constexpr int NT = 32 / KS;
  constexpr int ASUB = 8192;
  constexpr int BUFSZ = 28672;
  const int bm = bid % BMX;
  const int ht = (bid / BMX) & 7;
  const int ks = bid / (BMX * 8);
  const int t0 = ks * NT;
  const int tid = threadIdx.x;
  const int wid = tid >> 6, lane = tid & 63;
  const int lhi = lane >> 4, llo = lane & 15;
  const int q = wid;
  const unsigned short* hcprev = tp.hc[LEVEL - 1];

  int aOffL[2], aOffR[2];
#pragma unroll
  for (int ii = 0; ii < 2; ++ii) {
    int gi = ii * 4 + wid;
    int ar = gi * 16 + (lane >> 2);
    int ck = (lane & 3) ^ ((ar >> 1) & 3);
    int am = bm * 128 + ar;
    int b = am >> LOGNK, j = am & (NK - 1);
    int base = (b * NKP + 2 * j) * (2 * NH);
    aOffL[ii] = base + ck * 8;
    aOffR[ii] = base + 2 * NH + ck * 8;
  }

  int bOff[5];
#pragma unroll
  for (int ii = 0; ii < 5; ++ii) {
    int gi = ii * 4 + wid;
    if (gi < 20) {
      int r = gi * 16 + (lane >> 2);
      int gg = gi >> 2;
      int ck = (lane & 3) ^ ((r >> 1) & 3);
      bOff[ii] = ((2 * gg) * NH + (ht * 64 + (r & 63))) * NH + ck * 8;
    } else bOff[ii] = 0;
  }

  auto do_stage = [&](int buf, int tt) {
    unsigned char* base = lds + buf * BUFSZ;
    const int kw = (tt & 15) * 32;
    const int* ao = (tt < 16) ? aOffL : aOffR;
#pragma unroll
    for (int ii = 0; ii < 2; ++ii)
      glds16(hcprev + ao[ii] + kw, base + (ii * 4 + wid) * 1024);
    const size_t wsel = (size_t)(tt >> 4) * NH * NH;
#pragma unroll
    for (int ii = 0; ii < 5; ++ii) {
      int gi = ii * 4 + wid;
      if (gi < 20)
        glds16(tp.wbf + wsel + bOff[ii] + kw, base + ASUB + gi * 1024);
    }
  };

  int aoff[8], boff[5];
#pragma unroll
  for (int fm = 0; fm < 8; ++fm) {
    int r = fm * 16 + llo;
    aoff[fm] = r * 64 + ((lhi ^ ((r >> 1) & 3)) << 4);
  }
#pragma unroll
  for (int g = 0; g < 5; ++g) {
    int r = g * 64 + q * 16 + llo;
    boff[g] = ASUB + r * 64 + ((lhi ^ ((r >> 1) & 3)) << 4);
  }

  f4v acc[8][5];
#pragma unroll
  for (int fm = 0; fm < 8; ++fm)
#pragma unroll
    for (int g = 0; g < 5; ++g)
      acc[fm][g] = (f4v){0.f, 0.f, 0.f, 0.f};

  auto compute = [&](int buf) {
    const unsigned char* base = lds + buf * BUFSZ;
    s8v af[8], bv[5];
#pragma unroll
    for (int fm = 0; fm < 8; ++fm) af[fm] = *(const s8v*)(base + aoff[fm]);
#pragma unroll
    for (int g = 0; g < 5; ++g)  bv[g] = *(const s8v*)(base + boff[g]);
    __builtin_amdgcn_s_setprio(1);
#pragma unroll
    for (int fm = 0; fm < 8; ++fm)
#pragma unroll
      for (int g = 0; g < 5; ++g)
        acc[fm][g] = __builtin_amdgcn_mfma_f32_16x16x32_bf16(
            af[fm], bv[g], acc[fm][g], 0, 0, 0);
    __builtin_amdgcn_s_setprio(0);
  };

  do_stage(0, t0);
  __syncthreads();
  for (int t = 0; t < NT; ++t) {
    const int cur = t & 1;
    if (t + 1 < NT) do_stage(cur ^ 1, t0 + t + 1);
    compute(cur);
    __syncthreads();
  }

  const int hdl = q * 16 + llo;
  if constexpr (KS > 1) {
#pragma unroll
    for (int fm = 0; fm < 8; ++fm) {
#pragma unroll
      for (int jj = 0; jj < 4; ++jj) {
        int m = bm * 128 + fm * 16 + lhi * 4 + jj;
        size_t base = (((size_t)(ks * M + m) * 8 + ht) * 5) * 64;
#pragma unroll
        for (int g = 0; g < 5; ++g)
          tp.part[LEVEL][base + g * 64 + hdl] = f2bf(acc[fm][g][jj]);
      }
    }
  } else {
    const int hd = ht * 64 + hdl;
    float bb[5];
#pragma unroll
    for (int g = 0; g < 5; ++g) bb[g] = tp.bias[g][hd];
#pragma unroll
    for (int fm = 0; fm < 8; ++fm) {
#pragma unroll
      for (int jj = 0; jj < 4; ++jj) {
        int m = bm * 128 + fm * 16 + lhi * 4 + jj;
        int b = m >> LOGNK, j = m & (NK - 1);
        float zi  = acc[fm][0][jj] + bb[0];
        float zfl = acc[fm][1][jj] + bb[1];
        float zfr = acc[fm][2][jj] + bb[2];
        float zo  = acc[fm][3][jj] + bb[3];
        float zc  = acc[fm][4][jj] + bb[4];
        const unsigned short* cb = hcprev + ((size_t)b * NKP + 2 * j) * (2 * NH) + NH;
        float cl = bf2f(cb[hd]);
        float cr = bf2f(cb[2 * NH + hd]);
        float cnew = sigf(zi) * tanhf(zc) + sigf(zfl) * cl + sigf(zfr) * cr;
        float hnew = sigf(zo) * tanhf(cnew);
        unsigned short* orow = tp.hc[LEVEL] + ((size_t)b * NK + j) * (2 * NH);
        orow[hd] = f2bf(hnew);
        orow[NH + hd] = f2bf(cnew);
        int colout = (((j + 1) << LEVEL) - 2 - __popc(j)) + 1;
        tp.out[((size_t)b * NMAX + colout) * NH + hd] = hnew;
      }
    }
  }
}

template<int LEVEL, int KS>
__device__ void tail_combine(const TailP& tp, int bid) {
  constexpr int NK = NL >> LEVEL;
  constexpr int LOGNK = 8 - LEVEL;
  constexpr int NKP = NL >> (LEVEL - 1);
  constexpr int M = NB * NK;
  const unsigned short* part = tp.part[LEVEL];
  const unsigned short* hcprev = tp.hc[LEVEL - 1];
  for (int t = bid * 256 + threadIdx.x; t < M * 512; t += 256 * 256) {
    int m = t >> 9, hd = t & 511;
    int ht = hd >> 6, hdl = hd & 63;
    int b = m >> LOGNK, j = m & (NK - 1);
    float z[5];
#pragma unroll
    for (int g = 0; g < 5; ++g) z[g] = tp.bias[g][hd];
    for (int ks = 0; ks < KS; ++ks) {
      size_t base = (((size_t)(ks * M + m) * 8 + ht) * 5) * 64;
#pragma unroll
      for (int g = 0; g < 5; ++g) z[g] += bf2f(part[base + g * 64 + hdl]);
    }
    const unsigned short* cb = hcprev + ((size_t)b * NKP + 2 * j) * (2 * NH) + NH;
    float cl = bf2f(cb[hd]);
    float cr = bf2f(cb[2 * NH + hd]);
    float cnew = sigf(z[0]) * tanhf(z[4]) + sigf(z[1]) * cl + sigf(z[2]) * cr;
    float hnew = sigf(z[3]) * tanhf(cnew);
    unsigned short* orow = tp.hc[LEVEL] + ((size_t)b * NK + j) * (2 * NH);
    orow[hd] = f2bf(hnew);
    orow[NH + hd] = f2bf(cnew);
    int colout = (((j + 1) << LEVEL) - 2 - __popc(j)) + 1;
    tp.out[((size_t)b * NMAX + colout) * NH + hd] = hnew;
    if constexpr (LEVEL == 8) { tp.fh[b * NH + hd] = hnew; tp.fc[b * NH + hd] = cnew; }
  }
}

__global__ __launch_bounds__(256, 2)
void lstm_tail(TailP tp) {
  __shared__ __align__(16) unsigned char lds[57344];
  const int bid = blockIdx.x;
  tail_gemm<3, 1>(tp, lds, bid);
  gbar(tp.bar);
  tail_gemm<4, 2>(tp, lds, bid);
  gbar(tp.bar);
  tail_combine<4, 2>(tp, bid);
  gbar(tp.bar);
  tail_gemm<5, 4>(tp, lds, bid);
  gbar(tp.bar);
  tail_combine<5, 4>(tp, bid);
  gbar(tp.bar);
  tail_gemm<6, 8>(tp, lds, bid);
  gbar(tp.bar);
  tail_combine<6, 8>(tp, bid);
  gbar(tp.bar);
  tail_gemm<7, 16>(tp, lds, bid);
  gbar(tp.bar);
  tail_combine<7, 16>(tp, bid);
  gbar(tp.bar);
  tail_gemm<8, 32>(tp, lds, bid);
  gbar(tp.bar);
  tail_combine<8, 32>(tp, bid);
}

extern "C" void kernel_launch(void* const* d_in, const int* in_sizes, int n_in,
                              void* d_out, int out_size, void* d_ws, size_t ws_size,
                              hipStream_t stream) {
  unsigned short* wbf = (unsigned short*)d_ws;            // 5.24 MB
  unsigned short* R1  = wbf + (size_t)10 * NH * NH;       // 16,777,216 elems
  unsigned short* R2  = R1 + 16777216;                    // 16,777,216 elems
  // R1: embbf (level 1), then outputs of levels 2,4,6,8; split-K partials for
  // levels 5,7 at R1+4M (in-use prefix <= 2.1M).  Barrier words at R1+16M
  // (beyond all tail-phase writes; memset below runs after L2, stream-ordered).
  // R2: outputs of levels 1,3,5,7; partials L4 at R2+6M (prefix 4.19M),
  // L6/L8 at R2+4M (prefix <= 1.05M).

  PrepParams pp;
  for (int i = 0; i < 10; ++i) pp.u[i] = (const float*)d_in[2 + i];
  pp.emb  = (const float*)d_in[1];
  pp.wdst = wbf;
  pp.edst = R1;

  Params p;
  p.widx = (const int*)d_in[0];
  for (int g = 0; g < 5; ++g) p.bias[g] = (const float*)d_in[12 + g];
  p.wbf   = wbf;
  p.embbf = R1;
  p.out   = (float*)d_out;
  p.fh    = p.out + (size_t)NB * NMAX * NH;
  p.fc    = p.fh + NB * NH;

  prep_cvt<<<dim3(9280), dim3(256), 0, stream>>>(pp);

  unsigned short* lvlout[9];
  for (int k = 1; k <= 8; ++k) lvlout[k] = (k & 1) ? R2 : R1;

  p.hcprev = nullptr;     p.hcout = lvlout[1];
  lstm_level<1, 256><<<dim3(64, 8), dim3(512), 0, stream>>>(p);
  p.hcprev = lvlout[1];   p.hcout = lvlout[2];
  lstm_level<2, 128><<<dim3(64, 8), dim3(256), 0, stream>>>(p);

  int* bar = (int*)(R1 + 16000000);
  hipMemsetAsync(bar, 0, 64, stream);   // ws poisoned 0xAA once; re-zero each launch

  TailP tp;
  for (int g = 0; g < 5; ++g) tp.bias[g] = p.bias[g];
  tp.wbf = wbf;
  for (int k = 1; k <= 8; ++k) tp.hc[k] = lvlout[k];
  tp.hc[0] = nullptr;
  for (int k = 0; k < 9; ++k) tp.part[k] = nullptr;
  tp.part[4] = R2 + (size_t)6 * 1024 * 1024;
  tp.part[5] = R1 + (size_t)4 * 1024 * 1024;
  tp.part[6] = R2 + (size_t)4 * 1024 * 1024;
  tp.part[7] = R1 + (size_t)4 * 1024 * 1024;
  tp.part[8] = R2 + (size_t)4 * 1024 * 1024;
  tp.out = p.out;
  tp.fh  = p.fh;
  tp.fc  = p.fc;
  tp.bar = bar;
  lstm_tail<<<dim3(256), dim3(256), 0, stream>>>(tp);
}

// Round 13
// 358.581 us; speedup vs baseline: 2.9846x; 2.9846x over previous
//
#include <hip/hip_runtime.h>

#define NB 128
#define NL 256
#define NH 512
#define NMAX 256

typedef __attribute__((ext_vector_type(8))) short s8v;
typedef __attribute__((ext_vector_type(4))) float f4v;

struct Params {
  const int* widx;                 // (B, L) int32
  const float* bias[5];            // each (H,) f32: i, fl, fr, o, c
  const unsigned short* wbf;       // ws: 10 x (H,H) bf16, order [gate][side]
  const unsigned short* embbf;     // ws: (VOCAB, H) bf16 (valid during level 1)
  const unsigned short* hcprev;    // prev level: row (b*NKp + node)*2H, h@0 c@H
  unsigned short* hcout;           // this level: row (b*NK + node)*2H
  unsigned short* p1;              // split-K partials region 1 (chunks of 64 elems)
  unsigned short* p2;              // region 2
  int pthr;                        // chunk threshold: q<pthr -> p1, else p2
  float* out;                      // (B, 256, H) f32
  float* fh;                       // (B, H)
  float* fc;                       // (B, H)
};

struct PrepParams {
  const float* u[10];
  const float* emb;
  unsigned short* wdst;
  unsigned short* edst;
};

__device__ __forceinline__ float bf2f(unsigned short u) {
  union { unsigned int i; float f; } v;
  v.i = ((unsigned int)u) << 16;
  return v.f;
}
__device__ __forceinline__ unsigned short f2bf(float f) {
  union { float f; unsigned int i; } v;
  v.f = f;
  unsigned int x = v.i;
  x += 0x7fffu + ((x >> 16) & 1u);   // RNE
  return (unsigned short)(x >> 16);
}
__device__ __forceinline__ s8v pack8(f4v a, f4v b) {
  s8v r;
  r[0] = (short)f2bf(a[0]); r[1] = (short)f2bf(a[1]);
  r[2] = (short)f2bf(a[2]); r[3] = (short)f2bf(a[3]);
  r[4] = (short)f2bf(b[0]); r[5] = (short)f2bf(b[1]);
  r[6] = (short)f2bf(b[2]); r[7] = (short)f2bf(b[3]);
  return r;
}
__device__ __forceinline__ float sigf(float x) {
  return 1.f / (1.f + __expf(-x));
}
__device__ __forceinline__ void glds16(const void* g, void* l) {
  __builtin_amdgcn_global_load_lds(
      (const __attribute__((address_space(1))) unsigned int*)g,
      (__attribute__((address_space(3))) unsigned int*)l, 16, 0, 0);
}
// Partial chunk address: chunk q (64 bf16 elems) lives in p1 below pthr, p2 above.
__device__ __forceinline__ unsigned short* paddr(const Params& p, size_t q) {
  return (q < (size_t)p.pthr) ? (p.p1 + q * 64)
                              : (p.p2 + (q - (size_t)p.pthr) * 64);
}
__device__ __forceinline__ const unsigned short* paddrc(const Params& p, size_t q) {
  return (q < (size_t)p.pthr) ? (p.p1 + q * 64)
                              : (p.p2 + (q - (size_t)p.pthr) * 64);
}

// One prep pass: 10 (H,H) weights + the full emb table, f32 -> bf16.
__global__ __launch_bounds__(256) void prep_cvt(PrepParams pp) {
  int gid = blockIdx.x * 256 + threadIdx.x;
  const float* s;
  unsigned short* d;
  if (gid < 327680) {
    int mat = gid >> 15, off = (gid & 32767) * 8;
    s = pp.u[mat] + off;
    d = pp.wdst + (size_t)mat * NH * NH + off;
  } else {
    size_t off = (size_t)(gid - 327680) * 8;
    s = pp.emb + off;
    d = pp.edst + off;
  }
  f4v x0 = *(const f4v*)s;
  f4v x1 = *(const f4v*)(s + 4);
  *(s8v*)d = pack8(x0, x1);
}

// Post-order position of internal node (k, j): pos = (j+1)*2^k - 2 - popcount(j).
// Output column = pos + 1 (column 0 duplicates node (1,0)).
//
// GEMM kernel: BM rows x (5 gates x 64 hd) x K-range.  BM*2 threads.
// Wave (mh, q): 128 rows x (5 gates x 16 hd), acc[8][5]; all 5 gates of one
// output element in ONE thread.  Proven 2-phase double-buffered K-loop
// (syncthreads, 2 blocks/CU).  XOR swizzle chunk ^= (row>>1)&3.
// KS>1: split-K -- block ks computes K-tiles [ks*32/KS, ...), writes bf16
// z-partials via paddr(); a deterministic combine kernel sums + gates.

template<int LEVEL, int BM, int KS>
__global__ __launch_bounds__(BM * 2, 2)
void lstm_level(Params p) {
  constexpr int NK = NL >> LEVEL;
  constexpr int LOGNK = 8 - LEVEL;
  constexpr int NKP = NL >> (LEVEL - 1);
  constexpr int M = NB * NK;
  constexpr int W = BM / 32;                    // waves per block
  constexpr int ASUB = BM * 64;                 // A bytes per tile
  constexpr int BUFSZ = ASUB + 20480;
  constexpr int NT = 32 / KS;                   // K-tiles this block
  __shared__ __align__(16) unsigned char lds[2 * BUFSZ];

  const int tid = threadIdx.x;
  const int wid = tid >> 6;
  const int lane = tid & 63;
  const int lhi = lane >> 4, llo = lane & 15;
  const int mh = (BM == 256) ? (wid & 1) : 0;   // m-half (128 rows)
  const int q  = (BM == 256) ? (wid >> 1) : wid; // 16-hd slice
  const int bm = blockIdx.x, ht = blockIdx.y;
  const int ks = (KS > 1) ? blockIdx.z : 0;
  const int t0 = ks * NT;

  const unsigned short* abase = (LEVEL == 1) ? p.embbf : p.hcprev;

  // ---------- A staging: 2 glds/wave/tile; group gi = rows gi*16..+15 ----------
  int aOffL[2], aOffR[2];
#pragma unroll
  for (int ii = 0; ii < 2; ++ii) {
    int gi = ii * W + wid;
    int ar = gi * 16 + (lane >> 2);
    int ck = (lane & 3) ^ ((ar >> 1) & 3);
    int am = bm * BM + ar; if (am > M - 1) am = M - 1;
    int b = am >> LOGNK, j = am & (NK - 1);
    if constexpr (LEVEL == 1) {
      aOffL[ii] = p.widx[b * NL + 2 * j] * NH + ck * 8;
      aOffR[ii] = p.widx[b * NL + 2 * j + 1] * NH + ck * 8;
    } else {
      int base = (b * NKP + 2 * j) * (2 * NH);
      aOffL[ii] = base + ck * 8;
      aOffR[ii] = base + 2 * NH + ck * 8;
    }
  }

  // ---------- B staging: 20 groups of 16 rows; row = gate*64 + hd-in-tile ----------
  constexpr int BI = (20 + W - 1) / W;
  int bOff[BI];
#pragma unroll
  for (int ii = 0; ii < BI; ++ii) {
    int gi = ii * W + wid;
    if (gi < 20) {
      int r = gi * 16 + (lane >> 2);
      int gg = gi >> 2;
      int ck = (lane & 3) ^ ((r >> 1) & 3);
      bOff[ii] = ((2 * gg) * NH + (ht * 64 + (r & 63))) * NH + ck * 8;
    } else bOff[ii] = 0;
  }

  auto do_stage = [&](int buf, int tt) {
    unsigned char* base = lds + buf * BUFSZ;
    const int kw = (tt & 15) * 32;
    const int* ao = (tt < 16) ? aOffL : aOffR;
#pragma unroll
    for (int ii = 0; ii < 2; ++ii)
      glds16(abase + ao[ii] + kw, base + (ii * W + wid) * 1024);
    const size_t wsel = (size_t)(tt >> 4) * NH * NH;
#pragma unroll
    for (int ii = 0; ii < BI; ++ii) {
      int gi = ii * W + wid;
      if (gi < 20)
        glds16(p.wbf + wsel + bOff[ii] + kw, base + ASUB + gi * 1024);
    }
  };

  // ---------- fragment LDS byte offsets (swizzled reads, tile-relative) ----------
  int aoff[8], boff[5];
#pragma unroll
  for (int fm = 0; fm < 8; ++fm) {
    int r = mh * 128 + fm * 16 + llo;
    aoff[fm] = r * 64 + ((lhi ^ ((r >> 1) & 3)) << 4);
  }
#pragma unroll
  for (int g = 0; g < 5; ++g) {
    int r = g * 64 + q * 16 + llo;
    boff[g] = ASUB + r * 64 + ((lhi ^ ((r >> 1) & 3)) << 4);
  }

  f4v acc[8][5];
#pragma unroll
  for (int fm = 0; fm < 8; ++fm)
#pragma unroll
    for (int g = 0; g < 5; ++g)
      acc[fm][g] = (f4v){0.f, 0.f, 0.f, 0.f};

  auto compute = [&](int buf) {
    const unsigned char* base = lds + buf * BUFSZ;
    s8v af[8], bv[5];
#pragma unroll
    for (int fm = 0; fm < 8; ++fm) af[fm] = *(const s8v*)(base + aoff[fm]);
#pragma unroll
    for (int g = 0; g < 5; ++g)  bv[g] = *(const s8v*)(base + boff[g]);
    __builtin_amdgcn_s_setprio(1);
#pragma unroll
    for (int fm = 0; fm < 8; ++fm)
#pragma unroll
      for (int g = 0; g < 5; ++g)
        acc[fm][g] = __builtin_amdgcn_mfma_f32_16x16x32_bf16(
            af[fm], bv[g], acc[fm][g], 0, 0, 0);
    __builtin_amdgcn_s_setprio(0);
  };

  // ---------- K loop: NT tiles, double-buffered, one barrier per step ----------
  do_stage(0, t0);
  __syncthreads();
  for (int t = 0; t < NT; ++t) {
    const int cur = t & 1;
    if (t + 1 < NT) do_stage(cur ^ 1, t0 + t + 1);
    compute(cur);
    __syncthreads();
  }

  const int hdl = q * 16 + llo;

  if constexpr (KS > 1) {
    // ---------- partial epilogue: store acc as bf16 z-partials ----------
#pragma unroll
    for (int fm = 0; fm < 8; ++fm) {
#pragma unroll
      for (int jj = 0; jj < 4; ++jj) {
        int m = bm * BM + mh * 128 + fm * 16 + lhi * 4 + jj;
        size_t qb = ((size_t)(ks * M + m) * 8 + ht) * 5;
#pragma unroll
        for (int g = 0; g < 5; ++g)
          paddr(p, qb + g)[hdl] = f2bf(acc[fm][g][jj]);
      }
    }
  } else {
    // ---------- full epilogue: thread-local gate math ----------
    const int hd = ht * 64 + hdl;
    float bb[5];
#pragma unroll
    for (int g = 0; g < 5; ++g) bb[g] = p.bias[g][hd];

#pragma unroll
    for (int fm = 0; fm < 8; ++fm) {
#pragma unroll
      for (int jj = 0; jj < 4; ++jj) {
        int m = bm * BM + mh * 128 + fm * 16 + lhi * 4 + jj;
        if (m < M) {
          int b = m >> LOGNK, j = m & (NK - 1);
          float zi  = acc[fm][0][jj] + bb[0];
          float zfl = acc[fm][1][jj] + bb[1];
          float zfr = acc[fm][2][jj] + bb[2];
          float zo  = acc[fm][3][jj] + bb[3];
          float zc  = acc[fm][4][jj] + bb[4];
          float cl = 0.5f, cr = 0.5f;
          if constexpr (LEVEL > 1) {
            const unsigned short* cb =
                p.hcprev + ((size_t)b * NKP + 2 * j) * (2 * NH) + NH;
            cl = bf2f(cb[hd]);
            cr = bf2f(cb[2 * NH + hd]);
          }
          float cnew = sigf(zi) * tanhf(zc) + sigf(zfl) * cl + sigf(zfr) * cr;
          float hnew = sigf(zo) * tanhf(cnew);
          unsigned short* orow = p.hcout + ((size_t)b * NK + j) * (2 * NH);
          orow[hd] = f2bf(hnew);
          orow[NH + hd] = f2bf(cnew);
          int colout = (((j + 1) << LEVEL) - 2 - __popc(j)) + 1;
          p.out[((size_t)b * NMAX + colout) * NH + hd] = hnew;
          if (LEVEL == 1 && j == 0) p.out[(size_t)b * NMAX * NH + hd] = hnew;
        }
      }
    }
  }
}

// Split-K combine: sum KS bf16 z-partials in fixed order (deterministic),
// apply gates, write all outputs.  One thread per (m, hd).
template<int LEVEL, int KS>
__global__ __launch_bounds__(256)
void lstm_combine(Params p) {
  constexpr int NK = NL >> LEVEL;
  constexpr int LOGNK = 8 - LEVEL;
  constexpr int NKP = NL >> (LEVEL - 1);
  constexpr int M = NB * NK;
  int t = blockIdx.x * 256 + threadIdx.x;       // t < M*512
  int m = t >> 9, hd = t & 511;
  int ht = hd >> 6, hdl = hd & 63;
  int b = m >> LOGNK, j = m & (NK - 1);

  float z[5];
#pragma unroll
  for (int g = 0; g < 5; ++g) z[g] = p.bias[g][hd];
  for (int ks = 0; ks < KS; ++ks) {
    size_t qb = ((size_t)(ks * M + m) * 8 + ht) * 5;
#pragma unroll
    for (int g = 0; g < 5; ++g) z[g] += bf2f(paddrc(p, qb + g)[hdl]);
  }
  const unsigned short* cb = p.hcprev + ((size_t)b * NKP + 2 * j) * (2 * NH) + NH;
  float cl = bf2f(cb[hd]);
  float cr = bf2f(cb[2 * NH + hd]);
  float cnew = sigf(z[0]) * tanhf(z[4]) + sigf(z[1]) * cl + sigf(z[2]) * cr;
  float hnew = sigf(z[3]) * tanhf(cnew);
  unsigned short* orow = p.hcout + ((size_t)b * NK + j) * (2 * NH);
  orow[hd] = f2bf(hnew);
  orow[NH + hd] = f2bf(cnew);
  int colout = (((j + 1) << LEVEL) - 2 - __popc(j)) + 1;
  p.out[((size_t)b * NMAX + colout) * NH + hd] = hnew;
  if constexpr (LEVEL == 8) { p.fh[b * NH + hd] = hnew; p.fc[b * NH + hd] = cnew; }
}

extern "C" void kernel_launch(void* const* d_in, const int* in_sizes, int n_in,
                              void* d_out, int out_size, void* d_ws, size_t ws_size,
                              hipStream_t stream) {
  unsigned short* wbf = (unsigned short*)d_ws;            // 2,621,440 elems (5.24 MB)
  unsigned short* R1  = wbf + (size_t)10 * NH * NH;       // 16,777,216 elems
  unsigned short* R2  = R1 + 16777216;                    // 16,777,216 elems
  // R1: embbf (L1), then hc2 [0..8388608), hc4 [0..2097152), hc6 [0..524288),
  //     hc8 [0..131072).  R2: hc1 [0..16777216) (dead after L2), hc3
  //     [0..4194304), hc5 [0..1048576), hc7 [0..262144).
  // Split-K partials (chunks of 64 elems) live in exactly-free tails:
  //   L3 KS=2 : p1=R1+8388608 (131072 ch), p2=R2+4194304 (196608 ch) - exact.
  //   L4 KS=4 : p1=R1+2097152 (229376 ch), p2=R2+4194304 (98304 ch).
  //   L5 KS=4 : p1=R1+2097152 (163840 ch fit, single region).
  //   L6 KS=8 : p1=R1+524288.   L7 KS=16: p1=R2+262144.   L8 KS=32: p1=R1+131072.

  PrepParams pp;
  for (int i = 0; i < 10; ++i) pp.u[i] = (const float*)d_in[2 + i];
  pp.emb  = (const float*)d_in[1];
  pp.wdst = wbf;
  pp.edst = R1;

  Params p;
  p.widx = (const int*)d_in[0];
  for (int g = 0; g < 5; ++g) p.bias[g] = (const float*)d_in[12 + g];
  p.wbf   = wbf;
  p.embbf = R1;
  p.p1 = nullptr; p.p2 = nullptr; p.pthr = 1 << 28;
  p.out   = (float*)d_out;
  p.fh    = p.out + (size_t)NB * NMAX * NH;
  p.fc    = p.fh + NB * NH;

  prep_cvt<<<dim3(9280), dim3(256), 0, stream>>>(pp);

  unsigned short* lvlout[9];
  for (int k = 1; k <= 8; ++k) lvlout[k] = (k & 1) ? R2 : R1;

  p.hcprev = nullptr;     p.hcout = lvlout[1];
  lstm_level<1, 256, 1><<<dim3(64, 8), dim3(512), 0, stream>>>(p);
  p.hcprev = lvlout[1];   p.hcout = lvlout[2];
  lstm_level<2, 128, 1><<<dim3(64, 8), dim3(256), 0, stream>>>(p);

  // level 3: KS=2 (M=4096), chain 16, 512 blocks
  p.hcprev = lvlout[2];   p.hcout = lvlout[3];
  p.p1 = R1 + 8388608;  p.pthr = 131072;  p.p2 = R2 + 4194304;
  lstm_level<3, 128, 2><<<dim3(32, 8, 2), dim3(256), 0, stream>>>(p);
  lstm_combine<3, 2><<<dim3(8192), dim3(256), 0, stream>>>(p);

  // level 4: KS=4 (M=2048), chain 8, 512 blocks
  p.hcprev = lvlout[3];   p.hcout = lvlout[4];
  p.p1 = R1 + 2097152;  p.pthr = 229376;  p.p2 = R2 + 4194304;
  lstm_level<4, 128, 4><<<dim3(16, 8, 4), dim3(256), 0, stream>>>(p);
  lstm_combine<4, 4><<<dim3(4096), dim3(256), 0, stream>>>(p);

  // level 5: KS=4 (M=1024), chain 8, 256 blocks
  p.hcprev = lvlout[4];   p.hcout = lvlout[5];
  p.p1 = R1 + 2097152;  p.pthr = 229376;  p.p2 = R1 + 2097152;
  lstm_level<5, 128, 4><<<dim3(8, 8, 4), dim3(256), 0, stream>>>(p);
  lstm_combine<5, 4><<<dim3(2048), dim3(256), 0, stream>>>(p);

  // level 6: KS=8 (M=512), chain 4, 256 blocks
  p.hcprev = lvlout[5];   p.hcout = lvlout[6];
  p.p1 = R1 + 524288;   p.pthr = 1 << 28; p.p2 = p.p1;
  lstm_level<6, 128, 8><<<dim3(4, 8, 8), dim3(256), 0, stream>>>(p);
  lstm_combine<6, 8><<<dim3(1024), dim3(256), 0, stream>>>(p);

  // level 7: KS=16 (M=256), chain 2, 256 blocks
  p.hcprev = lvlout[6];   p.hcout = lvlout[7];
  p.p1 = R2 + 262144;   p.pthr = 1 << 28; p.p2 = p.p1;
  lstm_level<7, 128, 16><<<dim3(2, 8, 16), dim3(256), 0, stream>>>(p);
  lstm_combine<7, 16><<<dim3(512), dim3(256), 0, stream>>>(p);

  // level 8: KS=32 (M=128), chain 1, 256 blocks
  p.hcprev = lvlout[7];   p.hcout = lvlout[8];
  p.p1 = R1 + 131072;   p.pthr = 1 << 28; p.p2 = p.p1;
  lstm_level<8, 128, 32><<<dim3(1, 8, 32), dim3(256), 0, stream>>>(p);
  lstm_combine<8, 32><<<dim3(256), dim3(256), 0, stream>>>(p);
}

// Round 14
// 302.522 us; speedup vs baseline: 3.5377x; 1.1853x over previous
//
#include <hip/hip_runtime.h>

#define NB 128
#define NL 256
#define NH 512
#define NMAX 256

typedef __attribute__((ext_vector_type(8))) short s8v;
typedef __attribute__((ext_vector_type(4))) float f4v;

struct Params {
  const int* widx;                 // (B, L) int32
  const float* bias[5];            // each (H,) f32: i, fl, fr, o, c
  const unsigned short* wbf;       // ws: 10 x (H,H) bf16, order [gate][side]
  const unsigned short* embbf;     // ws: (VOCAB, H) bf16 (valid during level 1)
  const unsigned short* hcprev;    // prev level: row (b*NKp + node)*2H, h@0 c@H
  unsigned short* hcout;           // this level: row (b*NK + node)*2H
  unsigned short* part;            // split-K z-partials (bf16)
  float* out;                      // (B, 256, H) f32
  float* fh;                       // (B, H)
  float* fc;                       // (B, H)
};

struct PrepParams {
  const float* u[10];
  const float* emb;
  unsigned short* wdst;
  unsigned short* edst;
};

__device__ __forceinline__ float bf2f(unsigned short u) {
  union { unsigned int i; float f; } v;
  v.i = ((unsigned int)u) << 16;
  return v.f;
}
__device__ __forceinline__ unsigned short f2bf(float f) {
  union { float f; unsigned int i; } v;
  v.f = f;
  unsigned int x = v.i;
  x += 0x7fffu + ((x >> 16) & 1u);   // RNE
  return (unsigned short)(x >> 16);
}
__device__ __forceinline__ s8v pack8(f4v a, f4v b) {
  s8v r;
  r[0] = (short)f2bf(a[0]); r[1] = (short)f2bf(a[1]);
  r[2] = (short)f2bf(a[2]); r[3] = (short)f2bf(a[3]);
  r[4] = (short)f2bf(b[0]); r[5] = (short)f2bf(b[1]);
  r[6] = (short)f2bf(b[2]); r[7] = (short)f2bf(b[3]);
  return r;
}
__device__ __forceinline__ float sigf(float x) {
  return 1.f / (1.f + __expf(-x));
}
__device__ __forceinline__ void glds16(const void* g, void* l) {
  __builtin_amdgcn_global_load_lds(
      (const __attribute__((address_space(1))) unsigned int*)g,
      (__attribute__((address_space(3))) unsigned int*)l, 16, 0, 0);
}

// One prep pass: 10 (H,H) weights + the full emb table, f32 -> bf16.
__global__ __launch_bounds__(256) void prep_cvt(PrepParams pp) {
  int gid = blockIdx.x * 256 + threadIdx.x;
  const float* s;
  unsigned short* d;
  if (gid < 327680) {
    int mat = gid >> 15, off = (gid & 32767) * 8;
    s = pp.u[mat] + off;
    d = pp.wdst + (size_t)mat * NH * NH + off;
  } else {
    size_t off = (size_t)(gid - 327680) * 8;
    s = pp.emb + off;
    d = pp.edst + off;
  }
  f4v x0 = *(const f4v*)s;
  f4v x1 = *(const f4v*)(s + 4);
  *(s8v*)d = pack8(x0, x1);
}

// Post-order position of internal node (k, j): pos = (j+1)*2^k - 2 - popcount(j).
// Output column = pos + 1 (column 0 duplicates node (1,0)).
//
// GEMM kernel: BM rows x (5 gates x 64 hd) x K-range.  BM*2 threads.
// Wave (mh, q): 128 rows x (5 gates x 16 hd), acc[8][5]; all 5 gates of one
// output element in ONE thread.  Proven 2-phase double-buffered K-loop.
// XOR swizzle chunk ^= (row>>1)&3 (verified conflict-free).
// KS>1: split-K; deterministic combine kernel sums partials + applies gates.
// TILES>1 (L1): persistent block computes TILES bm-tiles at the same ht; the
// next tile's buffer-0 stage is issued BEFORE the previous epilogue so the
// gate math hides the staging latency, and the B slice stays L2-hot.

template<int LEVEL, int BM, int KS, int TILES>
__global__ __launch_bounds__(BM * 2, 2)
void lstm_level(Params p) {
  constexpr int NK = NL >> LEVEL;
  constexpr int LOGNK = 8 - LEVEL;
  constexpr int NKP = NL >> (LEVEL - 1);
  constexpr int M = NB * NK;
  constexpr int W = BM / 32;                    // waves per block
  constexpr int ASUB = BM * 64;                 // A bytes per tile
  constexpr int BUFSZ = ASUB + 20480;
  constexpr int NT = 32 / KS;                   // K-tiles per bm-tile (even)
  __shared__ __align__(16) unsigned char lds[2 * BUFSZ];

  const int tid = threadIdx.x;
  const int wid = tid >> 6;
  const int lane = tid & 63;
  const int lhi = lane >> 4, llo = lane & 15;
  const int mh = (BM == 256) ? (wid & 1) : 0;   // m-half (128 rows)
  const int q  = (BM == 256) ? (wid >> 1) : wid; // 16-hd slice
  const int ht = blockIdx.y;
  const int ks = (KS > 1) ? blockIdx.z : 0;
  const int t0 = ks * NT;

  const unsigned short* abase = (LEVEL == 1) ? p.embbf : p.hcprev;

  // ---------- A staging offsets (recomputed per bm-tile) ----------
  int aOffL[2], aOffR[2];
  auto computeA = [&](int bm) {
#pragma unroll
    for (int ii = 0; ii < 2; ++ii) {
      int gi = ii * W + wid;
      int ar = gi * 16 + (lane >> 2);
      int ck = (lane & 3) ^ ((ar >> 1) & 3);
      int am = bm * BM + ar; if (am > M - 1) am = M - 1;
      int b = am >> LOGNK, j = am & (NK - 1);
      if constexpr (LEVEL == 1) {
        aOffL[ii] = p.widx[b * NL + 2 * j] * NH + ck * 8;
        aOffR[ii] = p.widx[b * NL + 2 * j + 1] * NH + ck * 8;
      } else {
        int base = (b * NKP + 2 * j) * (2 * NH);
        aOffL[ii] = base + ck * 8;
        aOffR[ii] = base + 2 * NH + ck * 8;
      }
    }
  };

  // ---------- B staging: 20 groups of 16 rows; row = gate*64 + hd-in-tile ----------
  constexpr int BI = (20 + W - 1) / W;
  int bOff[BI];
#pragma unroll
  for (int ii = 0; ii < BI; ++ii) {
    int gi = ii * W + wid;
    if (gi < 20) {
      int r = gi * 16 + (lane >> 2);
      int gg = gi >> 2;
      int ck = (lane & 3) ^ ((r >> 1) & 3);
      bOff[ii] = ((2 * gg) * NH + (ht * 64 + (r & 63))) * NH + ck * 8;
    } else bOff[ii] = 0;
  }

  auto do_stage = [&](int buf, int tt) {
    unsigned char* base = lds + buf * BUFSZ;
    const int kw = (tt & 15) * 32;
    const int* ao = (tt < 16) ? aOffL : aOffR;
#pragma unroll
    for (int ii = 0; ii < 2; ++ii)
      glds16(abase + ao[ii] + kw, base + (ii * W + wid) * 1024);
    const size_t wsel = (size_t)(tt >> 4) * NH * NH;
#pragma unroll
    for (int ii = 0; ii < BI; ++ii) {
      int gi = ii * W + wid;
      if (gi < 20)
        glds16(p.wbf + wsel + bOff[ii] + kw, base + ASUB + gi * 1024);
    }
  };

  // ---------- fragment LDS byte offsets (swizzled reads, tile-relative) ----------
  int aoff[8], boff[5];
#pragma unroll
  for (int fm = 0; fm < 8; ++fm) {
    int r = mh * 128 + fm * 16 + llo;
    aoff[fm] = r * 64 + ((lhi ^ ((r >> 1) & 3)) << 4);
  }
#pragma unroll
  for (int g = 0; g < 5; ++g) {
    int r = g * 64 + q * 16 + llo;
    boff[g] = ASUB + r * 64 + ((lhi ^ ((r >> 1) & 3)) << 4);
  }

  f4v acc[8][5];

  auto compute = [&](int buf) {
    const unsigned char* base = lds + buf * BUFSZ;
    s8v af[8], bv[5];
#pragma unroll
    for (int fm = 0; fm < 8; ++fm) af[fm] = *(const s8v*)(base + aoff[fm]);
#pragma unroll
    for (int g = 0; g < 5; ++g)  bv[g] = *(const s8v*)(base + boff[g]);
    __builtin_amdgcn_s_setprio(1);
#pragma unroll
    for (int fm = 0; fm < 8; ++fm)
#pragma unroll
      for (int g = 0; g < 5; ++g)
        acc[fm][g] = __builtin_amdgcn_mfma_f32_16x16x32_bf16(
            af[fm], bv[g], acc[fm][g], 0, 0, 0);
    __builtin_amdgcn_s_setprio(0);
  };

  const int hdl = q * 16 + llo;
  float bb[5];
#pragma unroll
  for (int g = 0; g < 5; ++g) bb[g] = p.bias[g][ht * 64 + hdl];

  int bmCur = blockIdx.x * TILES;
  computeA(bmCur);
  do_stage(0, t0);

#pragma unroll
  for (int it = 0; it < TILES; ++it) {
#pragma unroll
    for (int fm = 0; fm < 8; ++fm)
#pragma unroll
      for (int g = 0; g < 5; ++g)
        acc[fm][g] = (f4v){0.f, 0.f, 0.f, 0.f};
    __syncthreads();
    // ---------- K loop: NT tiles, double-buffered ----------
    for (int t = 0; t < NT; ++t) {
      const int cur = t & 1;
      if (t + 1 < NT) do_stage(cur ^ 1, t0 + t + 1);
      compute(cur);
      if (t + 1 < NT) __syncthreads();
    }
    // All waves passed the (NT-2 -> NT-1) barrier: buf0 reads are done, so the
    // next tile's buf0 stage may issue now (last compute reads buf1).
    const int bmOut = bmCur;
    if (it + 1 < TILES) {
      bmCur = blockIdx.x * TILES + it + 1;
      computeA(bmCur);
      do_stage(0, t0);
    }

    if constexpr (KS > 1) {
      // ---------- partial epilogue: store acc as bf16 z-partials ----------
#pragma unroll
      for (int fm = 0; fm < 8; ++fm) {
#pragma unroll
        for (int jj = 0; jj < 4; ++jj) {
          int m = bmOut * BM + mh * 128 + fm * 16 + lhi * 4 + jj;
          size_t base = (((size_t)(ks * M + m) * 8 + ht) * 5) * 64;
#pragma unroll
          for (int g = 0; g < 5; ++g)
            p.part[base + g * 64 + hdl] = f2bf(acc[fm][g][jj]);
        }
      }
    } else {
      // ---------- full epilogue: thread-local gate math ----------
      const int hd = ht * 64 + hdl;
#pragma unroll
      for (int fm = 0; fm < 8; ++fm) {
#pragma unroll
        for (int jj = 0; jj < 4; ++jj) {
          int m = bmOut * BM + mh * 128 + fm * 16 + lhi * 4 + jj;
          if (m < M) {
            int b = m >> LOGNK, j = m & (NK - 1);
            float zi  = acc[fm][0][jj] + bb[0];
            float zfl = acc[fm][1][jj] + bb[1];
            float zfr = acc[fm][2][jj] + bb[2];
            float zo  = acc[fm][3][jj] + bb[3];
            float zc  = acc[fm][4][jj] + bb[4];
            float cl = 0.5f, cr = 0.5f;
            if constexpr (LEVEL > 1) {
              const unsigned short* cb =
                  p.hcprev + ((size_t)b * NKP + 2 * j) * (2 * NH) + NH;
              cl = bf2f(cb[hd]);
              cr = bf2f(cb[2 * NH + hd]);
            }
            float cnew = sigf(zi) * tanhf(zc) + sigf(zfl) * cl + sigf(zfr) * cr;
            float hnew = sigf(zo) * tanhf(cnew);
            unsigned short* orow = p.hcout + ((size_t)b * NK + j) * (2 * NH);
            orow[hd] = f2bf(hnew);
            orow[NH + hd] = f2bf(cnew);
            int colout = (((j + 1) << LEVEL) - 2 - __popc(j)) + 1;
            p.out[((size_t)b * NMAX + colout) * NH + hd] = hnew;
            if (LEVEL == 1 && j == 0) p.out[(size_t)b * NMAX * NH + hd] = hnew;
            if constexpr (LEVEL == 8) { p.fh[b * NH + hd] = hnew; p.fc[b * NH + hd] = cnew; }
          }
        }
      }
    }
  }
}

// Split-K combine: sum KS bf16 z-partials in fixed order (deterministic),
// apply gates, write all outputs.  One thread per (m, hd).
template<int LEVEL, int KS>
__global__ __launch_bounds__(256)
void lstm_combine(Params p) {
  constexpr int NK = NL >> LEVEL;
  constexpr int LOGNK = 8 - LEVEL;
  constexpr int NKP = NL >> (LEVEL - 1);
  constexpr int M = NB * NK;
  int t = blockIdx.x * 256 + threadIdx.x;       // t < M*512
  int m = t >> 9, hd = t & 511;
  int ht = hd >> 6, hdl = hd & 63;
  int b = m >> LOGNK, j = m & (NK - 1);

  float z[5];
#pragma unroll
  for (int g = 0; g < 5; ++g) z[g] = p.bias[g][hd];
  for (int ks = 0; ks < KS; ++ks) {
    size_t base = (((size_t)(ks * M + m) * 8 + ht) * 5) * 64;
#pragma unroll
    for (int g = 0; g < 5; ++g) z[g] += bf2f(p.part[base + g * 64 + hdl]);
  }
  const unsigned short* cb = p.hcprev + ((size_t)b * NKP + 2 * j) * (2 * NH) + NH;
  float cl = bf2f(cb[hd]);
  float cr = bf2f(cb[2 * NH + hd]);
  float cnew = sigf(z[0]) * tanhf(z[4]) + sigf(z[1]) * cl + sigf(z[2]) * cr;
  float hnew = sigf(z[3]) * tanhf(cnew);
  unsigned short* orow = p.hcout + ((size_t)b * NK + j) * (2 * NH);
  orow[hd] = f2bf(hnew);
  orow[NH + hd] = f2bf(cnew);
  int colout = (((j + 1) << LEVEL) - 2 - __popc(j)) + 1;
  p.out[((size_t)b * NMAX + colout) * NH + hd] = hnew;
  if constexpr (LEVEL == 8) { p.fh[b * NH + hd] = hnew; p.fc[b * NH + hd] = cnew; }
}

extern "C" void kernel_launch(void* const* d_in, const int* in_sizes, int n_in,
                              void* d_out, int out_size, void* d_ws, size_t ws_size,
                              hipStream_t stream) {
  unsigned short* wbf = (unsigned short*)d_ws;            // 2,621,440 elems (5.24 MB)
  unsigned short* R1  = wbf + (size_t)10 * NH * NH;       // 16,777,216 elems
  unsigned short* R2  = R1 + 16777216;                    // 16,777,216 elems
  // R1 holds embbf for level 1, then outputs of levels 2,4,6,8.
  // R2 holds outputs of levels 1,3,5,7.  Total ws use: 72.35 MB.
  // Split-K partials (r11-proven placement, all single-region, no overlap
  // with live hc prefixes):
  //   L4 KS=2: R2+6M (10.49M elems; hc3 prefix 4.19M)   L5 KS=4: R1+4M
  //   L6 KS=4: R2+4M   L7 KS=8: R1+4M   L8 KS=8: R2+4M

  PrepParams pp;
  for (int i = 0; i < 10; ++i) pp.u[i] = (const float*)d_in[2 + i];
  pp.emb  = (const float*)d_in[1];
  pp.wdst = wbf;
  pp.edst = R1;

  Params p;
  p.widx = (const int*)d_in[0];
  for (int g = 0; g < 5; ++g) p.bias[g] = (const float*)d_in[12 + g];
  p.wbf   = wbf;
  p.embbf = R1;
  p.part  = nullptr;
  p.out   = (float*)d_out;
  p.fh    = p.out + (size_t)NB * NMAX * NH;
  p.fc    = p.fh + NB * NH;

  prep_cvt<<<dim3(9280), dim3(256), 0, stream>>>(pp);

  unsigned short* lvlout[9];
  for (int k = 1; k <= 8; ++k) lvlout[k] = (k & 1) ? R2 : R1;

  // level 1: persistent 2-tile blocks (256 blocks, one residency round)
  p.hcprev = nullptr;     p.hcout = lvlout[1];
  lstm_level<1, 256, 1, 2><<<dim3(32, 8), dim3(512), 0, stream>>>(p);
  p.hcprev = lvlout[1];   p.hcout = lvlout[2];
  lstm_level<2, 128, 1, 1><<<dim3(64, 8), dim3(256), 0, stream>>>(p);
  p.hcprev = lvlout[2];   p.hcout = lvlout[3];
  lstm_level<3, 128, 1, 1><<<dim3(32, 8), dim3(256), 0, stream>>>(p);

  // level 4: KS=2 (M=2048)
  p.hcprev = lvlout[3];   p.hcout = lvlout[4];
  p.part   = lvlout[3] + 6 * 1024 * 1024;
  lstm_level<4, 128, 2, 1><<<dim3(16, 8, 2), dim3(256), 0, stream>>>(p);
  lstm_combine<4, 2><<<dim3(4096), dim3(256), 0, stream>>>(p);

  // level 5: KS=4 (M=1024)
  p.hcprev = lvlout[4];   p.hcout = lvlout[5];
  p.part   = lvlout[4] + 4 * 1024 * 1024;
  lstm_level<5, 128, 4, 1><<<dim3(8, 8, 4), dim3(256), 0, stream>>>(p);
  lstm_combine<5, 4><<<dim3(2048), dim3(256), 0, stream>>>(p);

  // level 6: KS=4 (M=512)
  p.hcprev = lvlout[5];   p.hcout = lvlout[6];
  p.part   = lvlout[5] + 4 * 1024 * 1024;
  lstm_level<6, 128, 4, 1><<<dim3(4, 8, 4), dim3(256), 0, stream>>>(p);
  lstm_combine<6, 4><<<dim3(1024), dim3(256), 0, stream>>>(p);

  // level 7: KS=8 (M=256)
  p.hcprev = lvlout[6];   p.hcout = lvlout[7];
  p.part   = lvlout[6] + 4 * 1024 * 1024;
  lstm_level<7, 128, 8, 1><<<dim3(2, 8, 8), dim3(256), 0, stream>>>(p);
  lstm_combine<7, 8><<<dim3(512), dim3(256), 0, stream>>>(p);

  // level 8: KS=8 (M=128)
  p.hcprev = lvlout[7];   p.hcout = lvlout[8];
  p.part   = lvlout[7] + 4 * 1024 * 1024;
  lstm_level<8, 128, 8, 1><<<dim3(1, 8, 8), dim3(256), 0, stream>>>(p);
  lstm_combine<8, 8><<<dim3(256), dim3(256), 0, stream>>>(p);
}